// Round 9
// baseline (131.532 us; speedup 1.0000x reference)
//
#include <hip/hip_runtime.h>
#include <hip/hip_cooperative_groups.h>

namespace cg = cooperative_groups;

// GNNEmbeds: 3-layer NNConv, scalar edge features.
// W(e) = attr_e*A + B  =>  msg_e = attr_e*(h[src]@A) + (h[src]@B)
// Per layer: U = h@A, V = h@B, R = h@root + bias; h_next = relu(R + gather(msgs)).
// Round-9: ONE cooperative kernel = R6's proven phase bodies + 2 grid syncs.
//  - Only U/V cross tiles; R stays in LDS (rs) across phases (no global trip).
//  - Edge scan runs ONCE; LDS edge list + pad register persist across phases.
//  - No global atomics anywhere; stores are plain float4.
// Block = 512 threads owns TR=4 dst rows; 256 blocks = 1/CU (co-resident).

#define HD    128
#define TR    4
#define CAP   192
#define CAPP  (CAP + 16)
#define NTHR  512
#define SCR   TR
#define KSPL  4

struct Tile {
    float hs[TR + 1][HD];               // gather accumulator (+ scratch row)
    float rs[TR][HD];                   // own-tile root term, phase-carried
    float pbuf[KSPL - 1][3][TR][HD];    // GEMM partials
    int   lrow[CAPP];
    int   lsrc[CAPP];
    float lattr[CAPP];
    int   lcnt;
};

struct P {
    const float* x; const int* ei; const float* attr;
    const float *lw1, *lb1, *root1, *bias1;
    const float *lw2, *lb2, *root2, *bias2;
    const float *lw3, *lb3, *root3, *bias3;
    float *U2, *V2, *U3, *V3, *out;
    int N, E;
};

__device__ __forceinline__ void fma4(float4& a, float s, const float4& w) {
    a.x = fmaf(s, w.x, a.x); a.y = fmaf(s, w.y, a.y);
    a.z = fmaf(s, w.z, a.z); a.w = fmaf(s, w.w, a.w);
}

// Scan edges once (R6 body): dst int4; src/attr loaded on match; list padded
// to a multiple of 16 with scratch-row dummies. First barrier orders hs init.
__device__ __forceinline__ int scan_edges(const int* __restrict__ ei,
                                          const float* __restrict__ attr,
                                          int E, int n0, Tile& g, int t)
{
    if (t == 0) g.lcnt = 0;
    __syncthreads();
    const int nq = E >> 2;
    const int4*   src4 = (const int4*)ei;
    const int4*   dst4 = (const int4*)(ei + E);
    const float4* at4  = (const float4*)attr;
#pragma unroll 4
    for (int i = t; i < nq; i += NTHR) {
        const int4 d = dst4[i];
        const unsigned r0 = (unsigned)(d.x - n0);
        const unsigned r1 = (unsigned)(d.y - n0);
        const unsigned r2 = (unsigned)(d.z - n0);
        const unsigned r3 = (unsigned)(d.w - n0);
        if ((r0 < TR) || (r1 < TR) || (r2 < TR) || (r3 < TR)) {
            const int4   s = src4[i];
            const float4 a = at4[i];
            if (r0 < TR) { int k = atomicAdd(&g.lcnt, 1); if (k < CAP) { g.lrow[k] = r0; g.lsrc[k] = s.x; g.lattr[k] = a.x; } }
            if (r1 < TR) { int k = atomicAdd(&g.lcnt, 1); if (k < CAP) { g.lrow[k] = r1; g.lsrc[k] = s.y; g.lattr[k] = a.y; } }
            if (r2 < TR) { int k = atomicAdd(&g.lcnt, 1); if (k < CAP) { g.lrow[k] = r2; g.lsrc[k] = s.z; g.lattr[k] = a.z; } }
            if (r3 < TR) { int k = atomicAdd(&g.lcnt, 1); if (k < CAP) { g.lrow[k] = r3; g.lsrc[k] = s.w; g.lattr[k] = a.w; } }
        }
    }
    for (int e = (E & ~3) + t; e < E; e += NTHR) {
        const unsigned r = (unsigned)(ei[E + e] - n0);
        if (r < TR) { int k = atomicAdd(&g.lcnt, 1); if (k < CAP) { g.lrow[k] = r; g.lsrc[k] = ei[e]; g.lattr[k] = attr[e]; } }
    }
    __syncthreads();
    int cnt = g.lcnt; if (cnt > CAP) cnt = CAP;
    const int pad = (cnt + 15) & ~15;
    if (t < pad - cnt) {
        const int k = cnt + t;
        g.lrow[k] = SCR; g.lsrc[k] = 0; g.lattr[k] = 0.f;
    }
    __syncthreads();
    return pad;
}

// hs[r] += a*U[s] + V[s]; 16 edges in flight x float4 lanes. (R6 body)
__device__ __forceinline__ void gather_uv(const float* __restrict__ U,
                                          const float* __restrict__ V,
                                          Tile& g, int pad, int t)
{
    const int el = t >> 5;
    const int c4 = (t & 31) << 2;
#pragma unroll 2
    for (int base = 0; base < pad; base += 16) {
        const int   i = base + el;
        const int   r = g.lrow[i];
        const int   s = g.lsrc[i];
        const float a = g.lattr[i];
        const float4 u = *(const float4*)(U + (size_t)s * HD + c4);
        const float4 v = *(const float4*)(V + (size_t)s * HD + c4);
        atomicAdd(&g.hs[r][c4 + 0], fmaf(a, u.x, v.x));
        atomicAdd(&g.hs[r][c4 + 1], fmaf(a, u.y, v.y));
        atomicAdd(&g.hs[r][c4 + 2], fmaf(a, u.z, v.z));
        atomicAdd(&g.hs[r][c4 + 3], fmaf(a, u.w, v.w));
    }
    __syncthreads();
}

__device__ __forceinline__ void relu_hs(Tile& g, int t) {
    for (int i = t; i < TR * HD; i += NTHR) {
        float* p = &g.hs[0][0] + i;
        *p = fmaxf(*p, 0.f);
    }
    __syncthreads();
}

// GEMM (R6 body): 16 groups = (kq, row); KB=8 JIT batches; pbuf reduce.
// U,V -> global; R(+bias) -> LDS rs (consumed by the same block next phase).
__device__ __forceinline__ void gemm3(Tile& g, int n0, int t,
    const float* __restrict__ Wa, const float* __restrict__ Wb,
    const float* __restrict__ Wr, const float* __restrict__ bias,
    float* __restrict__ U, float* __restrict__ V)
{
    const int colg = (t & 31) << 2;
    const int grp  = t >> 5;
    const int row  = grp & (TR - 1);
    const int kq   = grp >> 2;
    const int k0   = kq * (HD / KSPL);

    float4 acc0 = make_float4(0.f, 0.f, 0.f, 0.f);
    float4 acc1 = make_float4(0.f, 0.f, 0.f, 0.f);
    float4 acc2 = make_float4(0.f, 0.f, 0.f, 0.f);

#pragma unroll 1
    for (int kb = 0; kb < HD / KSPL; kb += 8) {
        const int kk = k0 + kb;
        float4 wav[8], wbv[8], wrv[8];
#pragma unroll
        for (int j = 0; j < 8; ++j) {
            const size_t o = (size_t)(kk + j) * HD + colg;
            wav[j] = *(const float4*)(Wa + o);
            wbv[j] = *(const float4*)(Wb + o);
            wrv[j] = *(const float4*)(Wr + o);
        }
        float hreg[8];
#pragma unroll
        for (int j = 0; j < 8; j += 4)
            *(float4*)&hreg[j] = *(const float4*)&g.hs[row][kk + j];
#pragma unroll
        for (int j = 0; j < 8; ++j) {
            fma4(acc0, hreg[j], wav[j]);
            fma4(acc1, hreg[j], wbv[j]);
            fma4(acc2, hreg[j], wrv[j]);
        }
    }

    if (kq != 0) {
        *(float4*)&g.pbuf[kq - 1][0][row][colg] = acc0;
        *(float4*)&g.pbuf[kq - 1][1][row][colg] = acc1;
        *(float4*)&g.pbuf[kq - 1][2][row][colg] = acc2;
    }
    __syncthreads();
    if (kq == 0) {
#pragma unroll
        for (int pp = 0; pp < KSPL - 1; ++pp) {
            const float4 p0 = *(const float4*)&g.pbuf[pp][0][row][colg];
            const float4 p1 = *(const float4*)&g.pbuf[pp][1][row][colg];
            const float4 p2 = *(const float4*)&g.pbuf[pp][2][row][colg];
            acc0.x += p0.x; acc0.y += p0.y; acc0.z += p0.z; acc0.w += p0.w;
            acc1.x += p1.x; acc1.y += p1.y; acc1.z += p1.z; acc1.w += p1.w;
            acc2.x += p2.x; acc2.y += p2.y; acc2.z += p2.z; acc2.w += p2.w;
        }
        const float4 bv = *(const float4*)(bias + colg);
        acc2.x += bv.x; acc2.y += bv.y; acc2.z += bv.z; acc2.w += bv.w;
        const size_t o = (size_t)(n0 + row) * HD + colg;
        *(float4*)(U + o) = acc0;
        *(float4*)(V + o) = acc1;
        *(float4*)&g.rs[row][colg] = acc2;     // R stays in LDS
    }
}

__global__ __launch_bounds__(NTHR) void fused(P p) {
    cg::grid_group grid = cg::this_grid();
    __shared__ Tile g;
    const int t = threadIdx.x;
    const int n0 = blockIdx.x * TR;
    const int colg = (t & 31) << 2;
    const int el = t >> 5;

    // ================= Phase A: layer-1 gather + layer-2 GEMM =================
    {   // hs = x@root1 + bias1  (TR*HD == NTHR)
        const int r = t >> 7, c = t & 127;
        const float x0 = p.x[(n0 + r) * 2 + 0], x1 = p.x[(n0 + r) * 2 + 1];
        g.hs[r][c] = fmaf(x0, p.root1[c], fmaf(x1, p.root1[HD + c], p.bias1[c]));
    }

    const int pad = scan_edges(p.ei, p.attr, p.E, n0, g, t);   // list persists

    {   // gather layer-1 messages on the fly from x (in_c = 2)
        const float4 A0 = *(const float4*)(p.lw1 + colg);
        const float4 A1 = *(const float4*)(p.lw1 + HD + colg);
        const float4 B0 = *(const float4*)(p.lb1 + colg);
        const float4 B1 = *(const float4*)(p.lb1 + HD + colg);
#pragma unroll 2
        for (int base = 0; base < pad; base += 16) {
            const int   i = base + el;
            const int   r = g.lrow[i];
            const int   s = g.lsrc[i];
            const float a = g.lattr[i];
            const float2 xv = *(const float2*)(p.x + (size_t)s * 2);
            atomicAdd(&g.hs[r][colg + 0], fmaf(a, fmaf(xv.x, A0.x, xv.y * A1.x), fmaf(xv.x, B0.x, xv.y * B1.x)));
            atomicAdd(&g.hs[r][colg + 1], fmaf(a, fmaf(xv.x, A0.y, xv.y * A1.y), fmaf(xv.x, B0.y, xv.y * B1.y)));
            atomicAdd(&g.hs[r][colg + 2], fmaf(a, fmaf(xv.x, A0.z, xv.y * A1.z), fmaf(xv.x, B0.z, xv.y * B1.z)));
            atomicAdd(&g.hs[r][colg + 3], fmaf(a, fmaf(xv.x, A0.w, xv.y * A1.w), fmaf(xv.x, B0.w, xv.y * B1.w)));
        }
        __syncthreads();
    }

    relu_hs(g, t);
    gemm3(g, n0, t, p.lw2, p.lb2, p.root2, p.bias2, p.U2, p.V2);

    grid.sync();   // U2,V2 visible device-wide

    // ================= Phase B: layer-2 gather + layer-3 GEMM =================
    if (t < TR * HD / 4)
        ((float4*)&g.hs[0][0])[t] = ((const float4*)&g.rs[0][0])[t];
    __syncthreads();

    gather_uv(p.U2, p.V2, g, pad, t);
    relu_hs(g, t);
    gemm3(g, n0, t, p.lw3, p.lb3, p.root3, p.bias3, p.U3, p.V3);

    grid.sync();   // U3,V3 visible device-wide

    // ================= Phase C: layer-3 gather -> out =================
    if (t < TR * HD / 4)
        ((float4*)&g.hs[0][0])[t] = ((const float4*)&g.rs[0][0])[t];
    __syncthreads();

    gather_uv(p.U3, p.V3, g, pad, t);

    if (t < TR * HD / 4)
        ((float4*)(p.out + (size_t)n0 * HD))[t] = ((const float4*)&g.hs[0][0])[t];
}

extern "C" void kernel_launch(void* const* d_in, const int* in_sizes, int n_in,
                              void* d_out, int out_size, void* d_ws, size_t ws_size,
                              hipStream_t stream) {
    P p;
    p.x     = (const float*)d_in[0];
    p.ei    = (const int*)  d_in[1];
    p.attr  = (const float*)d_in[2];
    p.lw1   = (const float*)d_in[3];
    p.lb1   = (const float*)d_in[4];
    p.root1 = (const float*)d_in[5];
    p.bias1 = (const float*)d_in[6];
    p.lw2   = (const float*)d_in[7];
    p.lb2   = (const float*)d_in[8];
    p.root2 = (const float*)d_in[9];
    p.bias2 = (const float*)d_in[10];
    p.lw3   = (const float*)d_in[11];
    p.lb3   = (const float*)d_in[12];
    p.root3 = (const float*)d_in[13];
    p.bias3 = (const float*)d_in[14];

    p.N = in_sizes[0] / 2;   // x: [N,2]
    p.E = in_sizes[1] / 2;   // edge_index: [2,E]

    float* ws = (float*)d_ws;
    p.U2  = ws + 0 * (size_t)p.N * HD;
    p.V2  = ws + 1 * (size_t)p.N * HD;
    p.U3  = ws + 2 * (size_t)p.N * HD;
    p.V3  = ws + 3 * (size_t)p.N * HD;
    p.out = (float*)d_out;

    const int nblk = p.N / TR;   // 256 blocks, 1 per CU
    void* args[] = { &p };
    hipLaunchCooperativeKernel((const void*)fused, dim3(nblk), dim3(NTHR),
                               args, 0, stream);
}

// Round 10
// 56.483 us; speedup vs baseline: 2.3287x; 2.3287x over previous
//
#include <hip/hip_runtime.h>

// GNNEmbeds: 3-layer NNConv, scalar edge features.
// W(e) = attr_e*A + B  =>  msg_e = attr_e*(h[src]@A) + (h[src]@B)
// Per layer: U = h@A, V = h@B, R = h@root + bias; h_next = relu(R + gather(msgs)).
// 3 dispatches (structural minimum: grid.sync costs ~25-30us, measured R9),
// gather-into-consumer, no global atomics.
// Round-10 = R6 (best, 60.5us) + only the proven-safe deltas:
//  - g2k persists its padded edge lists; g3k/g4k load them (no re-scan).
//    R6's gemm3 (16-group, pbuf reduce, 24 loads in flight) kept VERBATIM.
//  - relu folded into gemm3's LDS h-read (kills relu pass + barrier).
//  - g3k/g4k: hs-init and list-load overlap, single shared barrier.

#define HD    128
#define TR    4          // dst rows per tile -> N=1024 gives 256 blocks (1/CU)
#define CAP   192        // LDS edge-list capacity (mean 32/tile)
#define CAPP  (CAP + 16) // padded stride for persisted lists
#define NTHR  512
#define SCR   TR         // scratch row for pad edges
#define KSPL  4

struct Tile {
    float hs[TR + 1][HD];               // gather accumulator (+ scratch row)
    float pbuf[KSPL - 1][3][TR][HD];    // GEMM partials
    int   lrow[CAPP];
    int   lsrc[CAPP];
    float lattr[CAPP];
    int   lcnt;
};

__device__ __forceinline__ void fma4(float4& a, float s, const float4& w) {
    a.x = fmaf(s, w.x, a.x); a.y = fmaf(s, w.y, a.y);
    a.z = fmaf(s, w.z, a.z); a.w = fmaf(s, w.w, a.w);
}

// Scan edges (g2k only; R6 body): dst int4, src/attr loaded on match; list
// padded to multiple of 16 with scratch-row dummies. First barrier orders
// the caller's hs-init writes as well.
__device__ __forceinline__ int scan_edges(const int* __restrict__ ei,
                                          const float* __restrict__ attr,
                                          int E, int n0, Tile& g, int t)
{
    if (t == 0) g.lcnt = 0;
    __syncthreads();
    const int nq = E >> 2;
    const int4*   src4 = (const int4*)ei;
    const int4*   dst4 = (const int4*)(ei + E);
    const float4* at4  = (const float4*)attr;
#pragma unroll 4
    for (int i = t; i < nq; i += NTHR) {
        const int4 d = dst4[i];
        const unsigned r0 = (unsigned)(d.x - n0);
        const unsigned r1 = (unsigned)(d.y - n0);
        const unsigned r2 = (unsigned)(d.z - n0);
        const unsigned r3 = (unsigned)(d.w - n0);
        if ((r0 < TR) || (r1 < TR) || (r2 < TR) || (r3 < TR)) {
            const int4   s = src4[i];
            const float4 a = at4[i];
            if (r0 < TR) { int k = atomicAdd(&g.lcnt, 1); if (k < CAP) { g.lrow[k] = r0; g.lsrc[k] = s.x; g.lattr[k] = a.x; } }
            if (r1 < TR) { int k = atomicAdd(&g.lcnt, 1); if (k < CAP) { g.lrow[k] = r1; g.lsrc[k] = s.y; g.lattr[k] = a.y; } }
            if (r2 < TR) { int k = atomicAdd(&g.lcnt, 1); if (k < CAP) { g.lrow[k] = r2; g.lsrc[k] = s.z; g.lattr[k] = a.z; } }
            if (r3 < TR) { int k = atomicAdd(&g.lcnt, 1); if (k < CAP) { g.lrow[k] = r3; g.lsrc[k] = s.w; g.lattr[k] = a.w; } }
        }
    }
    for (int e = (E & ~3) + t; e < E; e += NTHR) {   // E%4 tail (empty here)
        const unsigned r = (unsigned)(ei[E + e] - n0);
        if (r < TR) { int k = atomicAdd(&g.lcnt, 1); if (k < CAP) { g.lrow[k] = r; g.lsrc[k] = ei[e]; g.lattr[k] = attr[e]; } }
    }
    __syncthreads();
    int cnt = g.lcnt; if (cnt > CAP) cnt = CAP;
    const int pad = (cnt + 15) & ~15;
    if (t < pad - cnt) {
        const int k = cnt + t;
        g.lrow[k] = SCR; g.lsrc[k] = 0; g.lattr[k] = 0.f;
    }
    __syncthreads();
    return pad;
}

// hs[r] += a*U[s] + V[s]; 16 edges in flight x float4 lanes. (R6 body)
__device__ __forceinline__ void gather_uv(const float* __restrict__ U,
                                          const float* __restrict__ V,
                                          Tile& g, int pad, int t)
{
    const int el = t >> 5;
    const int c4 = (t & 31) << 2;
#pragma unroll 2
    for (int base = 0; base < pad; base += 16) {
        const int   i = base + el;
        const int   r = g.lrow[i];
        const int   s = g.lsrc[i];
        const float a = g.lattr[i];
        const float4 u = *(const float4*)(U + (size_t)s * HD + c4);
        const float4 v = *(const float4*)(V + (size_t)s * HD + c4);
        atomicAdd(&g.hs[r][c4 + 0], fmaf(a, u.x, v.x));
        atomicAdd(&g.hs[r][c4 + 1], fmaf(a, u.y, v.y));
        atomicAdd(&g.hs[r][c4 + 2], fmaf(a, u.z, v.z));
        atomicAdd(&g.hs[r][c4 + 3], fmaf(a, u.w, v.w));
    }
    __syncthreads();
}

// GEMM (R6 body + relu fold): 16 groups = (kq, row); KB=8 JIT weight batches
// (24 independent float4 in flight); pbuf partial reduce; relu on the h-read.
template <bool RELU>
__device__ __forceinline__ void gemm3(Tile& g, int n0, int t,
    const float* __restrict__ Wa, const float* __restrict__ Wb,
    const float* __restrict__ Wr, const float* __restrict__ bias,
    float* __restrict__ U, float* __restrict__ V, float* __restrict__ R)
{
    const int colg = (t & 31) << 2;
    const int grp  = t >> 5;
    const int row  = grp & (TR - 1);
    const int kq   = grp >> 2;
    const int k0   = kq * (HD / KSPL);

    float4 acc0 = make_float4(0.f, 0.f, 0.f, 0.f);
    float4 acc1 = make_float4(0.f, 0.f, 0.f, 0.f);
    float4 acc2 = make_float4(0.f, 0.f, 0.f, 0.f);

#pragma unroll 1
    for (int kb = 0; kb < HD / KSPL; kb += 8) {
        const int kk = k0 + kb;
        float4 wav[8], wbv[8], wrv[8];
#pragma unroll
        for (int j = 0; j < 8; ++j) {
            const size_t o = (size_t)(kk + j) * HD + colg;
            wav[j] = *(const float4*)(Wa + o);
            wbv[j] = *(const float4*)(Wb + o);
            wrv[j] = *(const float4*)(Wr + o);
        }
        float hreg[8];
#pragma unroll
        for (int j = 0; j < 8; j += 4) {
            float4 h4 = *(const float4*)&g.hs[row][kk + j];
            if (RELU) {
                h4.x = fmaxf(h4.x, 0.f); h4.y = fmaxf(h4.y, 0.f);
                h4.z = fmaxf(h4.z, 0.f); h4.w = fmaxf(h4.w, 0.f);
            }
            *(float4*)&hreg[j] = h4;
        }
#pragma unroll
        for (int j = 0; j < 8; ++j) {
            fma4(acc0, hreg[j], wav[j]);
            fma4(acc1, hreg[j], wbv[j]);
            fma4(acc2, hreg[j], wrv[j]);
        }
    }

    if (kq != 0) {
        *(float4*)&g.pbuf[kq - 1][0][row][colg] = acc0;
        *(float4*)&g.pbuf[kq - 1][1][row][colg] = acc1;
        *(float4*)&g.pbuf[kq - 1][2][row][colg] = acc2;
    }
    __syncthreads();
    if (kq == 0) {
#pragma unroll
        for (int pp = 0; pp < KSPL - 1; ++pp) {
            const float4 p0 = *(const float4*)&g.pbuf[pp][0][row][colg];
            const float4 p1 = *(const float4*)&g.pbuf[pp][1][row][colg];
            const float4 p2 = *(const float4*)&g.pbuf[pp][2][row][colg];
            acc0.x += p0.x; acc0.y += p0.y; acc0.z += p0.z; acc0.w += p0.w;
            acc1.x += p1.x; acc1.y += p1.y; acc1.z += p1.z; acc1.w += p1.w;
            acc2.x += p2.x; acc2.y += p2.y; acc2.z += p2.z; acc2.w += p2.w;
        }
        const float4 bv = *(const float4*)(bias + colg);
        acc2.x += bv.x; acc2.y += bv.y; acc2.z += bv.z; acc2.w += bv.w;
        const size_t o = (size_t)(n0 + row) * HD + colg;
        *(float4*)(U + o) = acc0;
        *(float4*)(V + o) = acc1;
        *(float4*)(R + o) = acc2;
    }
}

// ---- G2: scan + layer-1 gather (msgs on the fly from x) + layer-2 GEMMs ----
__global__ __launch_bounds__(NTHR) void g2k(
    const float* __restrict__ x, const int* __restrict__ ei,
    const float* __restrict__ attr,
    const float* __restrict__ lw1, const float* __restrict__ lb1,
    const float* __restrict__ root1, const float* __restrict__ bias1,
    const float* __restrict__ lw2, const float* __restrict__ lb2,
    const float* __restrict__ root2, const float* __restrict__ bias2,
    float* __restrict__ U2, float* __restrict__ V2, float* __restrict__ R2,
    int* __restrict__ gecnt, int* __restrict__ gerow,
    int* __restrict__ gesrc, float* __restrict__ geattr,
    int E)
{
    __shared__ Tile g;
    const int t = threadIdx.x;
    const int n0 = blockIdx.x * TR;
    const int colg = (t & 31) << 2;

    // hs = x@root1 + bias1  (TR*HD == NTHR: one element per thread)
    {
        const int r = t >> 7, c = t & 127;
        const float x0 = x[(n0 + r) * 2 + 0], x1 = x[(n0 + r) * 2 + 1];
        g.hs[r][c] = fmaf(x0, root1[c], fmaf(x1, root1[HD + c], bias1[c]));
    }

    const int pad = scan_edges(ei, attr, E, n0, g, t);

    // persist padded list for g3k/g4k (plain global stores, no barrier needed)
    {
        const int base = blockIdx.x * CAPP;
        if (t < pad) {
            gerow[base + t]  = g.lrow[t];
            gesrc[base + t]  = g.lsrc[t];
            geattr[base + t] = g.lattr[t];
        }
        if (t == 0) gecnt[blockIdx.x] = pad;
    }

    // gather layer-1 messages: msg[c] = a*(x@A1)[c] + (x@B1)[c]
    const float4 A0 = *(const float4*)(lw1 + colg);
    const float4 A1 = *(const float4*)(lw1 + HD + colg);
    const float4 B0 = *(const float4*)(lb1 + colg);
    const float4 B1 = *(const float4*)(lb1 + HD + colg);
    const int el = t >> 5;
#pragma unroll 2
    for (int base = 0; base < pad; base += 16) {
        const int   i = base + el;
        const int   r = g.lrow[i];
        const int   s = g.lsrc[i];
        const float a = g.lattr[i];
        const float2 xv = *(const float2*)(x + (size_t)s * 2);
        atomicAdd(&g.hs[r][colg + 0], fmaf(a, fmaf(xv.x, A0.x, xv.y * A1.x), fmaf(xv.x, B0.x, xv.y * B1.x)));
        atomicAdd(&g.hs[r][colg + 1], fmaf(a, fmaf(xv.x, A0.y, xv.y * A1.y), fmaf(xv.x, B0.y, xv.y * B1.y)));
        atomicAdd(&g.hs[r][colg + 2], fmaf(a, fmaf(xv.x, A0.z, xv.y * A1.z), fmaf(xv.x, B0.z, xv.y * B1.z)));
        atomicAdd(&g.hs[r][colg + 3], fmaf(a, fmaf(xv.x, A0.w, xv.y * A1.w), fmaf(xv.x, B0.w, xv.y * B1.w)));
    }
    __syncthreads();

    gemm3<true>(g, n0, t, lw2, lb2, root2, bias2, U2, V2, R2);
}

// ---- G3: list-load + layer-2 gather + layer-3 GEMMs ----
__global__ __launch_bounds__(NTHR) void g3k(
    const float* __restrict__ U2, const float* __restrict__ V2,
    const float* __restrict__ R2,
    const float* __restrict__ lw3, const float* __restrict__ lb3,
    const float* __restrict__ root3, const float* __restrict__ bias3,
    float* __restrict__ U3, float* __restrict__ V3, float* __restrict__ R3,
    const int* __restrict__ gecnt, const int* __restrict__ gerow,
    const int* __restrict__ gesrc, const float* __restrict__ geattr)
{
    __shared__ Tile g;
    const int t = threadIdx.x;
    const int n0 = blockIdx.x * TR;

    // hs-init and list-load overlap; one shared barrier.
    if (t < TR * HD / 4)
        ((float4*)&g.hs[0][0])[t] = ((const float4*)(R2 + (size_t)n0 * HD))[t];
    const int pad = gecnt[blockIdx.x];
    {
        const int base = blockIdx.x * CAPP;
        if (t < pad) {
            g.lrow[t]  = gerow[base + t];
            g.lsrc[t]  = gesrc[base + t];
            g.lattr[t] = geattr[base + t];
        }
    }
    __syncthreads();

    gather_uv(U2, V2, g, pad, t);
    gemm3<true>(g, n0, t, lw3, lb3, root3, bias3, U3, V3, R3);
}

// ---- G4: list-load + layer-3 gather -> out (no relu, plain stores) ----
__global__ __launch_bounds__(NTHR) void g4k(
    const float* __restrict__ U3, const float* __restrict__ V3,
    const float* __restrict__ R3, float* __restrict__ out,
    const int* __restrict__ gecnt, const int* __restrict__ gerow,
    const int* __restrict__ gesrc, const float* __restrict__ geattr)
{
    __shared__ Tile g;
    const int t = threadIdx.x;
    const int n0 = blockIdx.x * TR;

    if (t < TR * HD / 4)
        ((float4*)&g.hs[0][0])[t] = ((const float4*)(R3 + (size_t)n0 * HD))[t];
    const int pad = gecnt[blockIdx.x];
    {
        const int base = blockIdx.x * CAPP;
        if (t < pad) {
            g.lrow[t]  = gerow[base + t];
            g.lsrc[t]  = gesrc[base + t];
            g.lattr[t] = geattr[base + t];
        }
    }
    __syncthreads();

    gather_uv(U3, V3, g, pad, t);

    if (t < TR * HD / 4)
        ((float4*)(out + (size_t)n0 * HD))[t] = ((const float4*)&g.hs[0][0])[t];
}

extern "C" void kernel_launch(void* const* d_in, const int* in_sizes, int n_in,
                              void* d_out, int out_size, void* d_ws, size_t ws_size,
                              hipStream_t stream) {
    const float* x     = (const float*)d_in[0];
    const int*   ei    = (const int*)  d_in[1];
    const float* attr  = (const float*)d_in[2];
    const float* lw1   = (const float*)d_in[3];
    const float* lb1   = (const float*)d_in[4];
    const float* root1 = (const float*)d_in[5];
    const float* bias1 = (const float*)d_in[6];
    const float* lw2   = (const float*)d_in[7];
    const float* lb2   = (const float*)d_in[8];
    const float* root2 = (const float*)d_in[9];
    const float* bias2 = (const float*)d_in[10];
    const float* lw3   = (const float*)d_in[11];
    const float* lb3   = (const float*)d_in[12];
    const float* root3 = (const float*)d_in[13];
    const float* bias3 = (const float*)d_in[14];

    const int N = in_sizes[0] / 2;   // x: [N,2]
    const int E = in_sizes[1] / 2;   // edge_index: [2,E]
    const int ntiles = N / TR;       // 256 blocks, ~1 per CU

    float* out = (float*)d_out;
    float* ws  = (float*)d_ws;
    float* U2 = ws + 0 * (size_t)N * HD;
    float* V2 = ws + 1 * (size_t)N * HD;
    float* R2 = ws + 2 * (size_t)N * HD;
    float* U3 = ws + 3 * (size_t)N * HD;
    float* V3 = ws + 4 * (size_t)N * HD;
    float* R3 = ws + 5 * (size_t)N * HD;
    int*   gecnt  = (int*)(ws + 6 * (size_t)N * HD);
    int*   gerow  = gecnt + ntiles;
    int*   gesrc  = gerow + (size_t)ntiles * CAPP;
    float* geattr = (float*)(gesrc + (size_t)ntiles * CAPP);

    g2k<<<ntiles, NTHR, 0, stream>>>(x, ei, attr, lw1, lb1, root1, bias1,
                                     lw2, lb2, root2, bias2, U2, V2, R2,
                                     gecnt, gerow, gesrc, geattr, E);
    g3k<<<ntiles, NTHR, 0, stream>>>(U2, V2, R2, lw3, lb3, root3, bias3,
                                     U3, V3, R3, gecnt, gerow, gesrc, geattr);
    g4k<<<ntiles, NTHR, 0, stream>>>(U3, V3, R3, out,
                                     gecnt, gerow, gesrc, geattr);
}